// Round 2
// baseline (345.804 us; speedup 1.0000x reference)
//
#include <hip/hip_runtime.h>

#define Bsz 2
#define Sq  4096
#define Dm  1024
#define NH  16
#define HD  64

typedef __attribute__((ext_vector_type(8))) short short8;   // 8 bf16 = 4 VGPRs
typedef __attribute__((ext_vector_type(4))) float f32x4;
typedef __attribute__((ext_vector_type(2))) __fp16 fp16x2;  // cvt_pkrtz result type
typedef __attribute__((ext_vector_type(4))) _Float16 half4v;
typedef __attribute__((ext_vector_type(8))) _Float16 half8v; // K=32 f16 MFMA operand

__device__ __forceinline__ unsigned short f2bf(float x) {
    unsigned int u = __float_as_uint(x);
    u += 0x7fffu + ((u >> 16) & 1u);            // round-to-nearest-even
    return (unsigned short)(u >> 16);
}

__device__ __forceinline__ void gl2lds16(const unsigned short* g, unsigned short* l) {
    __builtin_amdgcn_global_load_lds(
        (const __attribute__((address_space(1))) unsigned int*)g,
        (__attribute__((address_space(3))) unsigned int*)l, 16, 0, 0);
}

// ---------------------------------------------------------------------------
// fp32 -> bf16 bulk convert (X). 4 elems/thread.
// ---------------------------------------------------------------------------
__global__ __launch_bounds__(256) void cvt_bf16(const float4* __restrict__ in,
                                                ushort4* __restrict__ out) {
    const int i = blockIdx.x * 256 + threadIdx.x;
    const float4 v = in[i];
    ushort4 r;
    r.x = f2bf(v.x); r.y = f2bf(v.y); r.z = f2bf(v.z); r.w = f2bf(v.w);
    out[i] = r;
}

// ---------------------------------------------------------------------------
// Fused weight transpose: W[K][N] fp32 -> WtAll[z][N][K] bf16, z in {q,k,v,o}
// ---------------------------------------------------------------------------
__global__ __launch_bounds__(256) void wtrans4(const float* __restrict__ Wq,
                                               const float* __restrict__ Wk,
                                               const float* __restrict__ Wv,
                                               const float* __restrict__ Wo,
                                               unsigned short* __restrict__ WtAll) {
    __shared__ float tile[64][65];
    const int z = blockIdx.z;
    const float* W = (z == 0) ? Wq : (z == 1) ? Wk : (z == 2) ? Wv : Wo;
    unsigned short* Wt = WtAll + (size_t)z * Dm * Dm;
    const int k0 = blockIdx.y * 64, n0 = blockIdx.x * 64;
    const int t = threadIdx.x;
    #pragma unroll
    for (int i = 0; i < 16; ++i) {
        const int idx = t + i * 256, r = idx >> 6, c = idx & 63;
        tile[r][c] = W[(size_t)(k0 + r) * Dm + n0 + c];
    }
    __syncthreads();
    #pragma unroll
    for (int i = 0; i < 16; ++i) {
        const int idx = t + i * 256, rr = idx >> 6, cc = idx & 63;
        Wt[(size_t)(n0 + rr) * Dm + k0 + cc] = f2bf(tile[cc][rr]);
    }
}

// ===========================================================================
// Shared GEMM core: 128x128 tile, BK=32, bf16 MFMA, global_load_lds staging.
// ===========================================================================
struct GemmCtx {
    int wm, wn, quad, c16;
    f32x4 acc[4][4];
};

__device__ __forceinline__ void gemm_core(
    const unsigned short* __restrict__ A,
    const unsigned short* __restrict__ Bt,
    int bm, int bn, unsigned short* As, unsigned short* Bs, GemmCtx& cx)
{
    const int t    = threadIdx.x;
    const int w    = t >> 6;
    const int lane = t & 63;
    cx.quad = lane >> 4;
    cx.c16  = lane & 15;
    cx.wm = (w >> 1) * 64;
    cx.wn = (w & 1) * 64;

    #pragma unroll
    for (int i = 0; i < 4; ++i)
        #pragma unroll
        for (int j = 0; j < 4; ++j)
            cx.acc[i][j] = (f32x4){0.f, 0.f, 0.f, 0.f};

    const int srow = lane >> 2, soff = (lane & 3) * 8;
    const unsigned short* Ag0 = A  + (size_t)(bm + w * 16 + srow) * Dm + soff;
    const unsigned short* Ag1 = Ag0 + (size_t)64 * Dm;
    const unsigned short* Bg0 = Bt + (size_t)(bn + w * 16 + srow) * Dm + soff;
    const unsigned short* Bg1 = Bg0 + (size_t)64 * Dm;
    unsigned short* Al0 = As + (w * 16) * 32;
    unsigned short* Al1 = As + (64 + w * 16) * 32;
    unsigned short* Bl0 = Bs + (w * 16) * 32;
    unsigned short* Bl1 = Bs + (64 + w * 16) * 32;

    for (int k0 = 0; k0 < Dm; k0 += 32) {
        __syncthreads();
        gl2lds16(Ag0 + k0, Al0);
        gl2lds16(Ag1 + k0, Al1);
        gl2lds16(Bg0 + k0, Bl0);
        gl2lds16(Bg1 + k0, Bl1);
        __syncthreads();

        short8 af[4], bf[4];
        #pragma unroll
        for (int mt = 0; mt < 4; ++mt)
            af[mt] = *(const short8*)(As + (cx.wm + mt * 16 + cx.c16) * 32 + cx.quad * 8);
        #pragma unroll
        for (int nt = 0; nt < 4; ++nt)
            bf[nt] = *(const short8*)(Bs + (cx.wn + nt * 16 + cx.c16) * 32 + cx.quad * 8);
        #pragma unroll
        for (int mt = 0; mt < 4; ++mt)
            #pragma unroll
            for (int nt = 0; nt < 4; ++nt)
                cx.acc[mt][nt] = __builtin_amdgcn_mfma_f32_16x16x32_bf16(
                    af[mt], bf[nt], cx.acc[mt][nt], 0, 0, 0);
    }
}

// ---------------------------------------------------------------------------
// Fused QKV projection: A=Xb[8192,1024], Bt=WtAll (Wq|Wk|Wv rows, 3072x1024).
// ---------------------------------------------------------------------------
__global__ __launch_bounds__(256) void gemm_qkv(
    const unsigned short* __restrict__ A,
    const unsigned short* __restrict__ WtAll,
    const float* __restrict__ bq, const float* __restrict__ bk,
    const float* __restrict__ bv,
    unsigned short* __restrict__ Qh, unsigned short* __restrict__ Kh,
    unsigned short* __restrict__ Vt, float qscale)
{
    __shared__ unsigned short As[128 * 32];
    __shared__ unsigned short Bs[128 * 32];
    const int bm = blockIdx.y * 128;
    const int bn = blockIdx.x * 128;          // 0..3072
    GemmCtx cx;
    gemm_core(A, WtAll, bm, bn, As, Bs, cx);

    const int which = bn >> 10;               // 0=Q 1=K 2=V
    const float* bias = (which == 0) ? bq : (which == 1) ? bk : bv;
    const float osc = (which == 0) ? qscale : 1.0f;

    #pragma unroll
    for (int mt = 0; mt < 4; ++mt) {
        const int m0 = bm + cx.wm + mt * 16 + cx.quad * 4;
        #pragma unroll
        for (int nt = 0; nt < 4; ++nt) {
            const int n  = bn + cx.wn + nt * 16 + cx.c16;
            const int nl = n & 1023;
            const float bvv = bias[nl];
            const int h = (nl >> 6), d = nl & 63;
            if (which < 2) {
                unsigned short* C = (which == 0) ? Qh : Kh;
                #pragma unroll
                for (int r = 0; r < 4; ++r) {
                    const int m = m0 + r;
                    const int b = m >> 12, s = m & (Sq - 1);
                    C[((size_t)(b * NH + h) * Sq + s) * HD + d] =
                        f2bf((cx.acc[mt][nt][r] + bvv) * osc);
                }
            } else {
                const int b = m0 >> 12, s0 = m0 & (Sq - 1);
                union { fp16x2 h2[2]; unsigned int u[2]; } pk;
                pk.h2[0] = __builtin_amdgcn_cvt_pkrtz(cx.acc[mt][nt][0] + bvv,
                                                      cx.acc[mt][nt][1] + bvv);
                pk.h2[1] = __builtin_amdgcn_cvt_pkrtz(cx.acc[mt][nt][2] + bvv,
                                                      cx.acc[mt][nt][3] + bvv);
                *(uint2*)(Vt + ((size_t)(b * NH + h) * HD + d) * Sq + s0) =
                    make_uint2(pk.u[0], pk.u[1]);
            }
        }
    }
}

// ---------------------------------------------------------------------------
// Output projection: fp32 out = AO @ Wo^T + bo
// ---------------------------------------------------------------------------
__global__ __launch_bounds__(256) void gemm_o(
    const unsigned short* __restrict__ A,
    const unsigned short* __restrict__ Bt,
    const float* __restrict__ bias, float* __restrict__ C)
{
    __shared__ unsigned short As[128 * 32];
    __shared__ unsigned short Bs[128 * 32];
    const int bm = blockIdx.y * 128;
    const int bn = blockIdx.x * 128;
    GemmCtx cx;
    gemm_core(A, Bt, bm, bn, As, Bs, cx);

    #pragma unroll
    for (int mt = 0; mt < 4; ++mt) {
        const int m0 = bm + cx.wm + mt * 16 + cx.quad * 4;
        #pragma unroll
        for (int nt = 0; nt < 4; ++nt) {
            const int n = bn + cx.wn + nt * 16 + cx.c16;
            const float bvv = bias[n];
            #pragma unroll
            for (int r = 0; r < 4; ++r)
                C[(size_t)(m0 + r) * Dm + n] = cx.acc[mt][nt][r] + bvv;
        }
    }
}

// ---------------------------------------------------------------------------
// Flash attention v7: v6 + occupancy/de-convoy package.
//   - 128 queries/block (qg=2): grid 1024 blocks = 4 blocks/CU = 4 waves/SIMD.
//     Four independently-barriered blocks per CU de-phase, letting one block's
//     exp2/cvt VALU phase overlap another's MFMA phase (v6 counters: MFMA 70us
//     + VALU 64us = 134us of 137us total -> zero overlap convoy).
//   - XCD swizzle: xcd = wg&7 owns bh in [4*xcd,4*xcd+4) -> its 4MB L2 holds
//     exactly those heads' K+V (4 x 1MB) despite 2x re-read traffic.
//   - T5 s_setprio(1) around MFMA clusters (QK bursts, PV block).
// Q,K: bf16 [B*NH][Sq][64] (Q pre-scaled by 0.125*log2e). Vt: fp16 [B*NH][64][Sq].
// ---------------------------------------------------------------------------
__global__ __launch_bounds__(256, 4) void attn_mfma7(
    const unsigned short* __restrict__ Q,
    const unsigned short* __restrict__ K,
    const unsigned short* __restrict__ Vt,
    unsigned short* __restrict__ AO)
{
    __shared__ unsigned short Ks[2][64 * 64];   // [key][d] bf16, XOR-swizzled rows
    __shared__ unsigned short Vs[2][64 * 64];   // [d][pos] fp16, key-permuted + swz

    // XCD-grouped decode: xcd = wg&7 (dispatch round-robin), 128 blocks per XCD
    // cover bh in [4*xcd, 4*xcd+4) x all 32 q-tiles.
    const int wg  = blockIdx.x;               // 0..1023
    const int j   = wg >> 3;                  // 0..127 within XCD
    const int bh  = (wg & 7) * 4 + (j >> 5);  // 0..31
    const int qt  = j & 31;                   // 0..31 (128 queries each)
    const int b = bh >> 4, h = bh & 15;
    const int t    = threadIdx.x;
    const int w    = t >> 6;
    const int lane = t & 63;
    const int quad = lane >> 4;
    const int c16  = lane & 15;
    const size_t base = (size_t)bh * Sq * HD;

    // Q B-frags: 2 query-groups x 2 k-halves, held all kernel
    short8 qf[2][2];
    #pragma unroll
    for (int qg = 0; qg < 2; ++qg) {
        const unsigned short* qp =
            Q + base + (size_t)(qt * 128 + w * 32 + qg * 16 + c16) * HD;
        qf[qg][0] = *(const short8*)(qp + quad * 8);
        qf[qg][1] = *(const short8*)(qp + 32 + quad * 8);
    }

    f32x4 O[2][4];                 // [qg][d-group]
    f32x4 Lsum[2];
    #pragma unroll
    for (int qg = 0; qg < 2; ++qg) {
        Lsum[qg] = (f32x4){0.f, 0.f, 0.f, 0.f};
        #pragma unroll
        for (int g = 0; g < 4; ++g)
            O[qg][g] = (f32x4){0.f, 0.f, 0.f, 0.f};
    }
    half8v ones8;
    #pragma unroll
    for (int i = 0; i < 8; ++i) ones8[i] = (_Float16)1.f;

    // staging geometry: row = t>>2 (0..63), chunk = (t&3)*8 halfwords
    const int srow = t >> 2, sc4 = (t & 3) * 8;
    const int swr = (srow & 7) << 3;          // staging-row XOR swizzle (halfwords)
    // V key-permutation for 4-key subchunks starting at m (within 32-group)
    const int f0 = (sc4 < 16) ? sc4 * 2 : (sc4 - 16) * 2 + 4;        // {0,16,4,20}
    const int f1 = (sc4 + 4 < 16) ? (sc4 + 4) * 2 : (sc4 - 12) * 2 + 4; // {8,24,12,28}
    // swizzled staging columns
    const int kc0 = sc4 ^ swr, kc1 = (sc4 + 32) ^ swr;
    const int vc0 = f0 ^ swr, vc1 = f1 ^ swr;
    const int vc2 = (32 + f0) ^ swr, vc3 = (32 + f1) ^ swr;

    const unsigned short* kg = K  + base + (size_t)srow * HD + sc4;
    const unsigned short* vg = Vt + base + (size_t)srow * Sq + sc4;
    unsigned short* ksl = &Ks[0][0] + srow * 64;
    unsigned short* vsl = &Vs[0][0] + srow * 64;
    const int LBUF = 64 * 64;

    int4 kr0, kr1, vr0, vr1;
    kr0 = *(const int4*)(kg);
    kr1 = *(const int4*)(kg + 32);
    vr0 = *(const int4*)(vg);
    vr1 = *(const int4*)(vg + 32);
    *(int4*)(ksl + kc0) = kr0;
    *(int4*)(ksl + kc1) = kr1;
    *(uint2*)(vsl + vc0) = make_uint2(vr0.x, vr0.y);
    *(uint2*)(vsl + vc1) = make_uint2(vr0.z, vr0.w);
    *(uint2*)(vsl + vc2) = make_uint2(vr1.x, vr1.y);
    *(uint2*)(vsl + vc3) = make_uint2(vr1.z, vr1.w);

    for (int kt = 0; kt < Sq / 64; ++kt) {
        const int cur = kt & 1;
        if (kt + 1 < Sq / 64) {               // prefetch next tile into regs
            const unsigned short* kp = kg + (size_t)(kt + 1) * 64 * HD;
            const unsigned short* vp = vg + (kt + 1) * 64;
            kr0 = *(const int4*)(kp);
            kr1 = *(const int4*)(kp + 32);
            vr0 = *(const int4*)(vp);
            vr1 = *(const int4*)(vp + 32);
        }
        __syncthreads();

        const unsigned short* ksb = &Ks[cur][0];
        const unsigned short* vsb = &Vs[cur][0];

        // QK^T (swapped operands) -> exp2 -> f16 P frags (C-layout keys quad*4+r)
        half4v P4[2][4];          // [qg][nt]
        #pragma unroll
        for (int nt = 0; nt < 4; ++nt) {
            const int krow = nt * 16 + c16;
            const int ksw = (krow & 7) << 3;
            const short8 kf0 = *(const short8*)(ksb + krow * 64 + ((quad * 8) ^ ksw));
            const short8 kf1 = *(const short8*)(ksb + krow * 64 + ((32 + quad * 8) ^ ksw));
            f32x4 z[2];
            __builtin_amdgcn_s_setprio(1);
            #pragma unroll
            for (int qg = 0; qg < 2; ++qg) {
                z[qg] = (f32x4){0.f, 0.f, 0.f, 0.f};
                z[qg] = __builtin_amdgcn_mfma_f32_16x16x32_bf16(kf0, qf[qg][0], z[qg], 0, 0, 0);
                z[qg] = __builtin_amdgcn_mfma_f32_16x16x32_bf16(kf1, qf[qg][1], z[qg], 0, 0, 0);
            }
            __builtin_amdgcn_s_setprio(0);
            #pragma unroll
            for (int qg = 0; qg < 2; ++qg) {
                const float p0 = __builtin_amdgcn_exp2f(z[qg][0]);
                const float p1 = __builtin_amdgcn_exp2f(z[qg][1]);
                const float p2 = __builtin_amdgcn_exp2f(z[qg][2]);
                const float p3 = __builtin_amdgcn_exp2f(z[qg][3]);
                union { fp16x2 h2[2]; half4v h4; } pk;
                pk.h2[0] = __builtin_amdgcn_cvt_pkrtz(p0, p1);
                pk.h2[1] = __builtin_amdgcn_cvt_pkrtz(p2, p3);
                P4[qg][nt] = pk.h4;
            }
        }

        // concat adjacent 16-key frags -> K=32 A-operands (matches V perm)
        half8v P32[2][2];
        #pragma unroll
        for (int qg = 0; qg < 2; ++qg) {
            #pragma unroll
            for (int cc = 0; cc < 2; ++cc) {
                union { half4v h4[2]; half8v h8; } u;
                u.h4[0] = P4[qg][2 * cc];
                u.h4[1] = P4[qg][2 * cc + 1];
                P32[qg][cc] = u.h8;
            }
        }

        // O += P @ V ; Lsum += P @ ones   (K=32 f16 MFMA)
        __builtin_amdgcn_s_setprio(1);
        #pragma unroll
        for (int cc = 0; cc < 2; ++cc) {
            #pragma unroll
            for (int g = 0; g < 4; ++g) {
                const int vrow = g * 16 + c16;
                const half8v vf = *(const half8v*)
                    (vsb + vrow * 64 + ((cc * 32 + quad * 8) ^ ((vrow & 7) << 3)));
                #pragma unroll
                for (int qg = 0; qg < 2; ++qg)
                    O[qg][g] = __builtin_amdgcn_mfma_f32_16x16x32_f16(
                        P32[qg][cc], vf, O[qg][g], 0, 0, 0);
            }
            #pragma unroll
            for (int qg = 0; qg < 2; ++qg)
                Lsum[qg] = __builtin_amdgcn_mfma_f32_16x16x32_f16(
                    P32[qg][cc], ones8, Lsum[qg], 0, 0, 0);
        }
        __builtin_amdgcn_s_setprio(0);

        if (kt + 1 < Sq / 64) {               // write prefetched tile to other buf
            const int nb = cur ^ 1;
            *(int4*)(ksl + nb * LBUF + kc0) = kr0;
            *(int4*)(ksl + nb * LBUF + kc1) = kr1;
            unsigned short* vdst = vsl + nb * LBUF;
            *(uint2*)(vdst + vc0) = make_uint2(vr0.x, vr0.y);
            *(uint2*)(vdst + vc1) = make_uint2(vr0.z, vr0.w);
            *(uint2*)(vdst + vc2) = make_uint2(vr1.x, vr1.y);
            *(uint2*)(vdst + vc3) = make_uint2(vr1.z, vr1.w);
        }
    }

    // finalize: Lsum per-lane (all c16 identical); store
    #pragma unroll
    for (int qg = 0; qg < 2; ++qg) {
        float linv[4];
        #pragma unroll
        for (int r = 0; r < 4; ++r) linv[r] = 1.f / Lsum[qg][r];
        #pragma unroll
        for (int g = 0; g < 4; ++g) {
            const int col = h * HD + g * 16 + c16;
            #pragma unroll
            for (int r = 0; r < 4; ++r) {
                const int s = qt * 128 + w * 32 + qg * 16 + quad * 4 + r;
                AO[((size_t)(b * Sq + s)) * Dm + col] = f2bf(O[qg][g][r] * linv[r]);
            }
        }
    }
}

// ---------------------------------------------------------------------------
extern "C" void kernel_launch(void* const* d_in, const int* in_sizes, int n_in,
                              void* d_out, int out_size, void* d_ws, size_t ws_size,
                              hipStream_t stream)
{
    const float* X  = (const float*)d_in[0];
    const float* Wq = (const float*)d_in[1];
    const float* bq = (const float*)d_in[2];
    const float* Wk = (const float*)d_in[3];
    const float* bk = (const float*)d_in[4];
    const float* Wv = (const float*)d_in[5];
    const float* bv = (const float*)d_in[6];
    const float* Wo = (const float*)d_in[7];
    const float* bo = (const float*)d_in[8];
    float* out = (float*)d_out;

    unsigned short* ws = (unsigned short*)d_ws;
    const size_t NX = (size_t)Bsz * Sq * Dm;   // 8,388,608
    const size_t NW = (size_t)Dm * Dm;         // 1,048,576
    unsigned short* Xb    = ws; ws += NX;
    unsigned short* WtAll = ws; ws += 4 * NW;  // [Wq|Wk|Wv|Wo] transposed bf16
    unsigned short* Qh    = ws; ws += NX;
    unsigned short* Kh    = ws; ws += NX;
    unsigned short* Vt    = ws; ws += NX;
    unsigned short* AO    = ws; ws += NX;

    cvt_bf16<<<(int)(NX / 1024), 256, 0, stream>>>((const float4*)X, (ushort4*)Xb);
    wtrans4<<<dim3(16, 16, 4), 256, 0, stream>>>(Wq, Wk, Wv, Wo, WtAll);

    const float SCL = 0.18033688011112042f;    // 0.125 * log2(e)
    gemm_qkv<<<dim3(3 * Dm / 128, (Bsz * Sq) / 128), 256, 0, stream>>>(
        Xb, WtAll, bq, bk, bv, Qh, Kh, Vt, SCL);

    attn_mfma7<<<dim3(32 * 32), 256, 0, stream>>>(Qh, Kh, Vt, AO);

    gemm_o<<<dim3(Dm / 128, (Bsz * Sq) / 128), 256, 0, stream>>>(
        AO, WtAll + 3 * NW, bo, out);
}

// Round 3
// 316.681 us; speedup vs baseline: 1.0920x; 1.0920x over previous
//
#include <hip/hip_runtime.h>

#define Bsz 2
#define Sq  4096
#define Dm  1024
#define NH  16
#define HD  64

typedef __attribute__((ext_vector_type(8))) short short8;   // 8 bf16 = 4 VGPRs
typedef __attribute__((ext_vector_type(4))) float f32x4;
typedef __attribute__((ext_vector_type(2))) __fp16 fp16x2;  // cvt_pkrtz result type
typedef __attribute__((ext_vector_type(4))) _Float16 half4v;
typedef __attribute__((ext_vector_type(8))) _Float16 half8v; // K=32 f16 MFMA operand

__device__ __forceinline__ unsigned short f2bf(float x) {
    unsigned int u = __float_as_uint(x);
    u += 0x7fffu + ((u >> 16) & 1u);            // round-to-nearest-even
    return (unsigned short)(u >> 16);
}

__device__ __forceinline__ void gl2lds16(const unsigned short* g, unsigned short* l) {
    __builtin_amdgcn_global_load_lds(
        (const __attribute__((address_space(1))) unsigned int*)g,
        (__attribute__((address_space(3))) unsigned int*)l, 16, 0, 0);
}

// ---------------------------------------------------------------------------
// fp32 -> bf16 bulk convert (X). 4 elems/thread.
// ---------------------------------------------------------------------------
__global__ __launch_bounds__(256) void cvt_bf16(const float4* __restrict__ in,
                                                ushort4* __restrict__ out) {
    const int i = blockIdx.x * 256 + threadIdx.x;
    const float4 v = in[i];
    ushort4 r;
    r.x = f2bf(v.x); r.y = f2bf(v.y); r.z = f2bf(v.z); r.w = f2bf(v.w);
    out[i] = r;
}

// ---------------------------------------------------------------------------
// Fused weight transpose: W[K][N] fp32 -> WtAll[z][N][K] bf16, z in {q,k,v,o}
// ---------------------------------------------------------------------------
__global__ __launch_bounds__(256) void wtrans4(const float* __restrict__ Wq,
                                               const float* __restrict__ Wk,
                                               const float* __restrict__ Wv,
                                               const float* __restrict__ Wo,
                                               unsigned short* __restrict__ WtAll) {
    __shared__ float tile[64][65];
    const int z = blockIdx.z;
    const float* W = (z == 0) ? Wq : (z == 1) ? Wk : (z == 2) ? Wv : Wo;
    unsigned short* Wt = WtAll + (size_t)z * Dm * Dm;
    const int k0 = blockIdx.y * 64, n0 = blockIdx.x * 64;
    const int t = threadIdx.x;
    #pragma unroll
    for (int i = 0; i < 16; ++i) {
        const int idx = t + i * 256, r = idx >> 6, c = idx & 63;
        tile[r][c] = W[(size_t)(k0 + r) * Dm + n0 + c];
    }
    __syncthreads();
    #pragma unroll
    for (int i = 0; i < 16; ++i) {
        const int idx = t + i * 256, rr = idx >> 6, cc = idx & 63;
        Wt[(size_t)(n0 + rr) * Dm + k0 + cc] = f2bf(tile[cc][rr]);
    }
}

// ===========================================================================
// Shared GEMM core: 128x128 tile, BK=32, bf16 MFMA, global_load_lds staging.
// ===========================================================================
struct GemmCtx {
    int wm, wn, quad, c16;
    f32x4 acc[4][4];
};

__device__ __forceinline__ void gemm_core(
    const unsigned short* __restrict__ A,
    const unsigned short* __restrict__ Bt,
    int bm, int bn, unsigned short* As, unsigned short* Bs, GemmCtx& cx)
{
    const int t    = threadIdx.x;
    const int w    = t >> 6;
    const int lane = t & 63;
    cx.quad = lane >> 4;
    cx.c16  = lane & 15;
    cx.wm = (w >> 1) * 64;
    cx.wn = (w & 1) * 64;

    #pragma unroll
    for (int i = 0; i < 4; ++i)
        #pragma unroll
        for (int j = 0; j < 4; ++j)
            cx.acc[i][j] = (f32x4){0.f, 0.f, 0.f, 0.f};

    const int srow = lane >> 2, soff = (lane & 3) * 8;
    const unsigned short* Ag0 = A  + (size_t)(bm + w * 16 + srow) * Dm + soff;
    const unsigned short* Ag1 = Ag0 + (size_t)64 * Dm;
    const unsigned short* Bg0 = Bt + (size_t)(bn + w * 16 + srow) * Dm + soff;
    const unsigned short* Bg1 = Bg0 + (size_t)64 * Dm;
    unsigned short* Al0 = As + (w * 16) * 32;
    unsigned short* Al1 = As + (64 + w * 16) * 32;
    unsigned short* Bl0 = Bs + (w * 16) * 32;
    unsigned short* Bl1 = Bs + (64 + w * 16) * 32;

    for (int k0 = 0; k0 < Dm; k0 += 32) {
        __syncthreads();
        gl2lds16(Ag0 + k0, Al0);
        gl2lds16(Ag1 + k0, Al1);
        gl2lds16(Bg0 + k0, Bl0);
        gl2lds16(Bg1 + k0, Bl1);
        __syncthreads();

        short8 af[4], bf[4];
        #pragma unroll
        for (int mt = 0; mt < 4; ++mt)
            af[mt] = *(const short8*)(As + (cx.wm + mt * 16 + cx.c16) * 32 + cx.quad * 8);
        #pragma unroll
        for (int nt = 0; nt < 4; ++nt)
            bf[nt] = *(const short8*)(Bs + (cx.wn + nt * 16 + cx.c16) * 32 + cx.quad * 8);
        #pragma unroll
        for (int mt = 0; mt < 4; ++mt)
            #pragma unroll
            for (int nt = 0; nt < 4; ++nt)
                cx.acc[mt][nt] = __builtin_amdgcn_mfma_f32_16x16x32_bf16(
                    af[mt], bf[nt], cx.acc[mt][nt], 0, 0, 0);
    }
}

// ---------------------------------------------------------------------------
// Fused QKV projection: A=Xb[8192,1024], Bt=WtAll (Wq|Wk|Wv rows, 3072x1024).
// ---------------------------------------------------------------------------
__global__ __launch_bounds__(256) void gemm_qkv(
    const unsigned short* __restrict__ A,
    const unsigned short* __restrict__ WtAll,
    const float* __restrict__ bq, const float* __restrict__ bk,
    const float* __restrict__ bv,
    unsigned short* __restrict__ Qh, unsigned short* __restrict__ Kh,
    unsigned short* __restrict__ Vt, float qscale)
{
    __shared__ unsigned short As[128 * 32];
    __shared__ unsigned short Bs[128 * 32];
    const int bm = blockIdx.y * 128;
    const int bn = blockIdx.x * 128;          // 0..3072
    GemmCtx cx;
    gemm_core(A, WtAll, bm, bn, As, Bs, cx);

    const int which = bn >> 10;               // 0=Q 1=K 2=V
    const float* bias = (which == 0) ? bq : (which == 1) ? bk : bv;
    const float osc = (which == 0) ? qscale : 1.0f;

    #pragma unroll
    for (int mt = 0; mt < 4; ++mt) {
        const int m0 = bm + cx.wm + mt * 16 + cx.quad * 4;
        #pragma unroll
        for (int nt = 0; nt < 4; ++nt) {
            const int n  = bn + cx.wn + nt * 16 + cx.c16;
            const int nl = n & 1023;
            const float bvv = bias[nl];
            const int h = (nl >> 6), d = nl & 63;
            if (which < 2) {
                unsigned short* C = (which == 0) ? Qh : Kh;
                #pragma unroll
                for (int r = 0; r < 4; ++r) {
                    const int m = m0 + r;
                    const int b = m >> 12, s = m & (Sq - 1);
                    C[((size_t)(b * NH + h) * Sq + s) * HD + d] =
                        f2bf((cx.acc[mt][nt][r] + bvv) * osc);
                }
            } else {
                const int b = m0 >> 12, s0 = m0 & (Sq - 1);
                union { fp16x2 h2[2]; unsigned int u[2]; } pk;
                pk.h2[0] = __builtin_amdgcn_cvt_pkrtz(cx.acc[mt][nt][0] + bvv,
                                                      cx.acc[mt][nt][1] + bvv);
                pk.h2[1] = __builtin_amdgcn_cvt_pkrtz(cx.acc[mt][nt][2] + bvv,
                                                      cx.acc[mt][nt][3] + bvv);
                *(uint2*)(Vt + ((size_t)(b * NH + h) * HD + d) * Sq + s0) =
                    make_uint2(pk.u[0], pk.u[1]);
            }
        }
    }
}

// ---------------------------------------------------------------------------
// Output projection: fp32 out = AO @ Wo^T + bo
// ---------------------------------------------------------------------------
__global__ __launch_bounds__(256) void gemm_o(
    const unsigned short* __restrict__ A,
    const unsigned short* __restrict__ Bt,
    const float* __restrict__ bias, float* __restrict__ C)
{
    __shared__ unsigned short As[128 * 32];
    __shared__ unsigned short Bs[128 * 32];
    const int bm = blockIdx.y * 128;
    const int bn = blockIdx.x * 128;
    GemmCtx cx;
    gemm_core(A, Bt, bm, bn, As, Bs, cx);

    #pragma unroll
    for (int mt = 0; mt < 4; ++mt) {
        const int m0 = bm + cx.wm + mt * 16 + cx.quad * 4;
        #pragma unroll
        for (int nt = 0; nt < 4; ++nt) {
            const int n = bn + cx.wn + nt * 16 + cx.c16;
            const float bvv = bias[n];
            #pragma unroll
            for (int r = 0; r < 4; ++r)
                C[(size_t)(m0 + r) * Dm + n] = cx.acc[mt][nt][r] + bvv;
        }
    }
}

// ---------------------------------------------------------------------------
// Flash attention v8: qg=4 (v6 LDS economy) + intra-wave software pipeline.
//   v6/v7 counters showed MfmaUtil+VALUBusy ~= 100% of duration: the per-nt
//   "MFMA then exp-of-that-MFMA" order serializes the two pipes. Restructure:
//     QK(nt) MFMA burst || exp(nt-1) VALU   (no data dependency -> co-issue)
//     PV(cc0) MFMA      || exp(nt3) + K-staging ds_writes
//     PV(cc1) MFMA      || V-staging ds_writes
//   sched_barrier(0) after each MFMA burst stops the compiler from clustering
//   all exps on one side. XCD-grouped grid (4 bh per XCD -> K/V L2-resident,
//   v7-proven: FETCH 139->27MB). Swizzled LDS (conflict-free reads) retained.
// Q,K: bf16 [B*NH][Sq][64] (Q pre-scaled by 0.125*log2e). Vt: fp16 [B*NH][64][Sq].
// ---------------------------------------------------------------------------
__global__ __launch_bounds__(256, 2) void attn_mfma8(
    const unsigned short* __restrict__ Q,
    const unsigned short* __restrict__ K,
    const unsigned short* __restrict__ Vt,
    unsigned short* __restrict__ AO)
{
    __shared__ unsigned short Ks[2][64 * 64];   // [key][d] bf16, XOR-swizzled rows
    __shared__ unsigned short Vs[2][64 * 64];   // [d][pos] fp16, key-permuted + swz

    // XCD-grouped decode: xcd = wg&7, 64 blocks per XCD cover 4 bh x 16 qt.
    const int wg  = blockIdx.x;               // 0..511
    const int j   = wg >> 3;                  // 0..63 within XCD
    const int bh  = (wg & 7) * 4 + (j >> 4);  // 0..31
    const int qt  = j & 15;                   // 0..15 (256 queries each)
    const int b = bh >> 4, h = bh & 15;
    const int t    = threadIdx.x;
    const int w    = t >> 6;
    const int lane = t & 63;
    const int quad = lane >> 4;
    const int c16  = lane & 15;
    const size_t base = (size_t)bh * Sq * HD;

    // Q B-frags: 4 query-groups x 2 k-halves, held all kernel
    short8 qf[4][2];
    #pragma unroll
    for (int qg = 0; qg < 4; ++qg) {
        const unsigned short* qp =
            Q + base + (size_t)(qt * 256 + w * 64 + qg * 16 + c16) * HD;
        qf[qg][0] = *(const short8*)(qp + quad * 8);
        qf[qg][1] = *(const short8*)(qp + 32 + quad * 8);
    }

    f32x4 O[4][4];                 // [qg][d-group]
    f32x4 Lsum[4];
    #pragma unroll
    for (int qg = 0; qg < 4; ++qg) {
        Lsum[qg] = (f32x4){0.f, 0.f, 0.f, 0.f};
        #pragma unroll
        for (int g = 0; g < 4; ++g)
            O[qg][g] = (f32x4){0.f, 0.f, 0.f, 0.f};
    }
    half8v ones8;
    #pragma unroll
    for (int i = 0; i < 8; ++i) ones8[i] = (_Float16)1.f;

    // staging geometry: row = t>>2 (0..63), chunk = (t&3)*8 halfwords
    const int srow = t >> 2, sc4 = (t & 3) * 8;
    const int swr = (srow & 7) << 3;          // staging-row XOR swizzle (halfwords)
    // V key-permutation for 4-key subchunks starting at m (within 32-group)
    const int f0 = (sc4 < 16) ? sc4 * 2 : (sc4 - 16) * 2 + 4;        // {0,16,4,20}
    const int f1 = (sc4 + 4 < 16) ? (sc4 + 4) * 2 : (sc4 - 12) * 2 + 4; // {8,24,12,28}
    // swizzled staging columns
    const int kc0 = sc4 ^ swr, kc1 = (sc4 + 32) ^ swr;
    const int vc0 = f0 ^ swr, vc1 = f1 ^ swr;
    const int vc2 = (32 + f0) ^ swr, vc3 = (32 + f1) ^ swr;

    const unsigned short* kg = K  + base + (size_t)srow * HD + sc4;
    const unsigned short* vg = Vt + base + (size_t)srow * Sq + sc4;
    unsigned short* ksl = &Ks[0][0] + srow * 64;
    unsigned short* vsl = &Vs[0][0] + srow * 64;
    const int LBUF = 64 * 64;

    int4 kr0, kr1, vr0, vr1;
    kr0 = *(const int4*)(kg);
    kr1 = *(const int4*)(kg + 32);
    vr0 = *(const int4*)(vg);
    vr1 = *(const int4*)(vg + 32);
    *(int4*)(ksl + kc0) = kr0;
    *(int4*)(ksl + kc1) = kr1;
    *(uint2*)(vsl + vc0) = make_uint2(vr0.x, vr0.y);
    *(uint2*)(vsl + vc1) = make_uint2(vr0.z, vr0.w);
    *(uint2*)(vsl + vc2) = make_uint2(vr1.x, vr1.y);
    *(uint2*)(vsl + vc3) = make_uint2(vr1.z, vr1.w);

    for (int kt = 0; kt < Sq / 64; ++kt) {
        const int cur = kt & 1;
        if (kt + 1 < Sq / 64) {               // prefetch next tile into regs
            const unsigned short* kp = kg + (size_t)(kt + 1) * 64 * HD;
            const unsigned short* vp = vg + (kt + 1) * 64;
            kr0 = *(const int4*)(kp);
            kr1 = *(const int4*)(kp + 32);
            vr0 = *(const int4*)(vp);
            vr1 = *(const int4*)(vp + 32);
        }
        __syncthreads();

        const unsigned short* ksb = &Ks[cur][0];
        const unsigned short* vsb = &Vs[cur][0];

        f32x4 z0[4], z1[4], z2[4], z3[4];
        half4v P4[4][4];          // [nt][qg]

        // --- pipeline stages ---------------------------------------------
        auto qkstep = [&](int nt5, f32x4* z) {
            const int krow = nt5 * 16 + c16;
            const int ksw = (krow & 7) << 3;
            const short8 kf0 = *(const short8*)(ksb + krow * 64 + ((quad * 8) ^ ksw));
            const short8 kf1 = *(const short8*)(ksb + krow * 64 + ((32 + quad * 8) ^ ksw));
            __builtin_amdgcn_s_setprio(1);
            #pragma unroll
            for (int qg = 0; qg < 4; ++qg) {
                f32x4 zz = (f32x4){0.f, 0.f, 0.f, 0.f};
                zz = __builtin_amdgcn_mfma_f32_16x16x32_bf16(kf0, qf[qg][0], zz, 0, 0, 0);
                zz = __builtin_amdgcn_mfma_f32_16x16x32_bf16(kf1, qf[qg][1], zz, 0, 0, 0);
                z[qg] = zz;
            }
            __builtin_amdgcn_s_setprio(0);
            __builtin_amdgcn_sched_barrier(0);
        };
        auto expstep = [&](const f32x4* z, half4v* Pn) {
            #pragma unroll
            for (int qg = 0; qg < 4; ++qg) {
                const float p0 = __builtin_amdgcn_exp2f(z[qg][0]);
                const float p1 = __builtin_amdgcn_exp2f(z[qg][1]);
                const float p2 = __builtin_amdgcn_exp2f(z[qg][2]);
                const float p3 = __builtin_amdgcn_exp2f(z[qg][3]);
                union { fp16x2 h2[2]; half4v h4; } pk;
                pk.h2[0] = __builtin_amdgcn_cvt_pkrtz(p0, p1);
                pk.h2[1] = __builtin_amdgcn_cvt_pkrtz(p2, p3);
                Pn[qg] = pk.h4;
            }
        };
        auto pvstep = [&](int cc) {
            half8v P32[4];
            #pragma unroll
            for (int qg = 0; qg < 4; ++qg) {
                union { half4v h4[2]; half8v h8; } u;
                u.h4[0] = P4[2 * cc][qg];
                u.h4[1] = P4[2 * cc + 1][qg];
                P32[qg] = u.h8;
            }
            half8v vf[4];
            #pragma unroll
            for (int g = 0; g < 4; ++g) {
                const int vrow = g * 16 + c16;
                vf[g] = *(const half8v*)
                    (vsb + vrow * 64 + ((cc * 32 + quad * 8) ^ ((vrow & 7) << 3)));
            }
            __builtin_amdgcn_s_setprio(1);
            #pragma unroll
            for (int g = 0; g < 4; ++g)
                #pragma unroll
                for (int qg = 0; qg < 4; ++qg)
                    O[qg][g] = __builtin_amdgcn_mfma_f32_16x16x32_f16(
                        P32[qg], vf[g], O[qg][g], 0, 0, 0);
            #pragma unroll
            for (int qg = 0; qg < 4; ++qg)
                Lsum[qg] = __builtin_amdgcn_mfma_f32_16x16x32_f16(
                    P32[qg], ones8, Lsum[qg], 0, 0, 0);
            __builtin_amdgcn_s_setprio(0);
            __builtin_amdgcn_sched_barrier(0);
        };

        // --- rotated schedule: MFMA(n) || VALU(n-1) ----------------------
        qkstep(0, z0);
        qkstep(1, z1);  expstep(z0, P4[0]);
        qkstep(2, z2);  expstep(z1, P4[1]);
        qkstep(3, z3);  expstep(z2, P4[2]);
        pvstep(0);
        expstep(z3, P4[3]);
        if (kt + 1 < Sq / 64) {               // K staging under PV(cc0) shadow
            const int nb = cur ^ 1;
            *(int4*)(ksl + nb * LBUF + kc0) = kr0;
            *(int4*)(ksl + nb * LBUF + kc1) = kr1;
        }
        pvstep(1);
        if (kt + 1 < Sq / 64) {               // V staging under PV(cc1) shadow
            const int nb = cur ^ 1;
            unsigned short* vdst = vsl + nb * LBUF;
            *(uint2*)(vdst + vc0) = make_uint2(vr0.x, vr0.y);
            *(uint2*)(vdst + vc1) = make_uint2(vr0.z, vr0.w);
            *(uint2*)(vdst + vc2) = make_uint2(vr1.x, vr1.y);
            *(uint2*)(vdst + vc3) = make_uint2(vr1.z, vr1.w);
        }
    }

    // finalize: Lsum per-lane (all c16 identical); store
    #pragma unroll
    for (int qg = 0; qg < 4; ++qg) {
        float linv[4];
        #pragma unroll
        for (int r = 0; r < 4; ++r) linv[r] = 1.f / Lsum[qg][r];
        #pragma unroll
        for (int g = 0; g < 4; ++g) {
            const int col = h * HD + g * 16 + c16;
            #pragma unroll
            for (int r = 0; r < 4; ++r) {
                const int s = qt * 256 + w * 64 + qg * 16 + quad * 4 + r;
                AO[((size_t)(b * Sq + s)) * Dm + col] = f2bf(O[qg][g][r] * linv[r]);
            }
        }
    }
}

// ---------------------------------------------------------------------------
extern "C" void kernel_launch(void* const* d_in, const int* in_sizes, int n_in,
                              void* d_out, int out_size, void* d_ws, size_t ws_size,
                              hipStream_t stream)
{
    const float* X  = (const float*)d_in[0];
    const float* Wq = (const float*)d_in[1];
    const float* bq = (const float*)d_in[2];
    const float* Wk = (const float*)d_in[3];
    const float* bk = (const float*)d_in[4];
    const float* Wv = (const float*)d_in[5];
    const float* bv = (const float*)d_in[6];
    const float* Wo = (const float*)d_in[7];
    const float* bo = (const float*)d_in[8];
    float* out = (float*)d_out;

    unsigned short* ws = (unsigned short*)d_ws;
    const size_t NX = (size_t)Bsz * Sq * Dm;   // 8,388,608
    const size_t NW = (size_t)Dm * Dm;         // 1,048,576
    unsigned short* Xb    = ws; ws += NX;
    unsigned short* WtAll = ws; ws += 4 * NW;  // [Wq|Wk|Wv|Wo] transposed bf16
    unsigned short* Qh    = ws; ws += NX;
    unsigned short* Kh    = ws; ws += NX;
    unsigned short* Vt    = ws; ws += NX;
    unsigned short* AO    = ws; ws += NX;

    cvt_bf16<<<(int)(NX / 1024), 256, 0, stream>>>((const float4*)X, (ushort4*)Xb);
    wtrans4<<<dim3(16, 16, 4), 256, 0, stream>>>(Wq, Wk, Wv, Wo, WtAll);

    const float SCL = 0.18033688011112042f;    // 0.125 * log2(e)
    gemm_qkv<<<dim3(3 * Dm / 128, (Bsz * Sq) / 128), 256, 0, stream>>>(
        Xb, WtAll, bq, bk, bv, Qh, Kh, Vt, SCL);

    attn_mfma8<<<dim3(512), 256, 0, stream>>>(Qh, Kh, Vt, AO);

    gemm_o<<<dim3(Dm / 128, (Bsz * Sq) / 128), 256, 0, stream>>>(
        AO, WtAll + 3 * NW, bo, out);
}